// Round 1
// baseline (346.333 us; speedup 1.0000x reference)
//
#include <hip/hip_runtime.h>
#include <hip/hip_bf16.h>

// MHA forward: B=2, S=2048, D_MODEL=1024, H=16, D_K=64. fp32 in/out, bf16 MFMA compute.
// ws layout (ushort elems): qb 0, kb 4M, vb 8M, wq 12M, wk 13M, wv 14M, wo 15M,
//   Qh 16M, Kh 20M, Vh 24M, attn 28M  -> total 32M ushorts = 64 MB (assumes ws_size >= 64MB).

typedef __attribute__((ext_vector_type(8))) short short8;
typedef __attribute__((ext_vector_type(4))) float f32x4;

__device__ __forceinline__ unsigned short f2b(float f) {
  union { float f; unsigned u; } x; x.f = f;
  unsigned r = (x.u + 0x7FFFu + ((x.u >> 16) & 1u)) >> 16;
  return (unsigned short)r;
}

__device__ __forceinline__ int swz7(int row) { return ((row ^ (row >> 3)) & 7) << 4; }

__device__ __forceinline__ void gload16(const void* g, void* l) {
  __builtin_amdgcn_global_load_lds((const __attribute__((address_space(1))) void*)g,
                                   (__attribute__((address_space(3))) void*)l, 16, 0, 0);
}

// ---------------- fp32 -> bf16 convert ----------------
__global__ __launch_bounds__(256) void cvt_bf16(const float* __restrict__ s,
                                                unsigned short* __restrict__ d, int n) {
  int i = (blockIdx.x * 256 + threadIdx.x) * 8;
  if (i >= n) return;
  float4 a = *(const float4*)(s + i);
  float4 b = *(const float4*)(s + i + 4);
  short8 o;
  o[0] = (short)f2b(a.x); o[1] = (short)f2b(a.y); o[2] = (short)f2b(a.z); o[3] = (short)f2b(a.w);
  o[4] = (short)f2b(b.x); o[5] = (short)f2b(b.y); o[6] = (short)f2b(b.z); o[7] = (short)f2b(b.w);
  *(short8*)(d + i) = o;
}

// ---------------- GEMM: out[m,n] = sum_k A[m,k]*W[n,k] + bias[n] ----------------
// A: [4096][1024] bf16 row-major. W: [1024][1024] bf16 (N rows x K). K=N=1024, M=4096.
// MODE 0: bf16 out, per-head layout [B][H][S][64].  MODE 1: fp32 out, [4096][1024].
template <int MODE>
__global__ __launch_bounds__(256, 2) void gemm_bt(const unsigned short* __restrict__ A,
                                                  const unsigned short* __restrict__ W,
                                                  const float* __restrict__ bias,
                                                  void* __restrict__ Out) {
  constexpr int K = 1024;
  const int m0 = blockIdx.y * 128, n0 = blockIdx.x * 128;
  __shared__ __align__(16) unsigned short At[128 * 64];
  __shared__ __align__(16) unsigned short Bt[128 * 64];
  const int t = threadIdx.x;
  const int w = t >> 6, l = t & 63;
  const int wr = w >> 1, wc = w & 1;
  const int lr = l & 15, hi = l >> 4;
  f32x4 acc[4][4] = {};
  for (int kt = 0; kt < 16; ++kt) {
    __syncthreads();
#pragma unroll
    for (int i = 0; i < 4; ++i) {  // stage A tile: 128 rows x 64 cols bf16, swizzled source
      int c = i * 256 + t;
      int row = c >> 3, cb = (c & 7) * 16;
      const char* src = (const char*)(A + (size_t)(m0 + row) * K + kt * 64);
      gload16(src + (cb ^ swz7(row)), At + c * 8);
    }
#pragma unroll
    for (int i = 0; i < 4; ++i) {  // stage B tile
      int c = i * 256 + t;
      int row = c >> 3, cb = (c & 7) * 16;
      const char* src = (const char*)(W + (size_t)(n0 + row) * K + kt * 64);
      gload16(src + (cb ^ swz7(row)), Bt + c * 8);
    }
    __syncthreads();
#pragma unroll
    for (int ks = 0; ks < 2; ++ks) {
      short8 af[4], bf[4];
#pragma unroll
      for (int mt = 0; mt < 4; ++mt) {
        int row = wr * 64 + mt * 16 + lr;
        af[mt] = *(const short8*)((const char*)At + row * 128 + ((ks * 64 + hi * 16) ^ swz7(row)));
      }
#pragma unroll
      for (int nt = 0; nt < 4; ++nt) {
        int row = wc * 64 + nt * 16 + lr;
        bf[nt] = *(const short8*)((const char*)Bt + row * 128 + ((ks * 64 + hi * 16) ^ swz7(row)));
      }
#pragma unroll
      for (int mt = 0; mt < 4; ++mt)
#pragma unroll
        for (int nt = 0; nt < 4; ++nt)
          acc[mt][nt] = __builtin_amdgcn_mfma_f32_16x16x32_bf16(af[mt], bf[nt], acc[mt][nt], 0, 0, 0);
    }
  }
#pragma unroll
  for (int nt = 0; nt < 4; ++nt) {
    int n = n0 + wc * 64 + nt * 16 + lr;
    float bn = bias[n];
#pragma unroll
    for (int mt = 0; mt < 4; ++mt) {
#pragma unroll
      for (int r = 0; r < 4; ++r) {
        int m = m0 + wr * 64 + mt * 16 + hi * 4 + r;
        float v = acc[mt][nt][r] + bn;
        if (MODE == 0) {
          size_t dst = ((size_t)((m >> 11) * 16 + (n >> 6))) * (2048 * 64) +
                       (size_t)(m & 2047) * 64 + (n & 63);
          ((unsigned short*)Out)[dst] = f2b(v);
        } else {
          ((float*)Out)[(size_t)m * 1024 + n] = v;
        }
      }
    }
  }
}

// ---------------- flash attention: one block = one (b,h) x 64 Q rows ----------------
__global__ __launch_bounds__(256, 2) void attn_fwd(const unsigned short* __restrict__ Q,
                                                   const unsigned short* __restrict__ Kh,
                                                   const unsigned short* __restrict__ Vh,
                                                   unsigned short* __restrict__ Oout) {
  const int bh = blockIdx.x >> 5, qt = blockIdx.x & 31;
  const int t = threadIdx.x, w = t >> 6, l = t & 63;
  const int lr = l & 15, hi = l >> 4;
  __shared__ __align__(16) unsigned short Kl[64 * 64];
  __shared__ __align__(16) unsigned short Vt[64 * 64];  // transposed: [d=64][kv=64]
  __shared__ __align__(16) unsigned short Pl[4][16 * 64];
  const unsigned short* Qb = Q + (size_t)bh * 2048 * 64;
  const unsigned short* Kb = Kh + (size_t)bh * 2048 * 64;
  const unsigned short* Vb = Vh + (size_t)bh * 2048 * 64;
  short8 qf[2];
#pragma unroll
  for (int ks = 0; ks < 2; ++ks)
    qf[ks] = *(const short8*)(Qb + (size_t)(qt * 64 + w * 16 + lr) * 64 + ks * 32 + hi * 8);
  f32x4 oacc[4] = {};
  float mrow[4], lrow[4];
#pragma unroll
  for (int r = 0; r < 4; ++r) { mrow[r] = -1e30f; lrow[r] = 0.f; }

  for (int kt = 0; kt < 32; ++kt) {
    __syncthreads();
#pragma unroll
    for (int i = 0; i < 2; ++i) {  // K tile [64 kv][64 d], swizzled source -> linear LDS
      int c = i * 256 + t;
      int row = c >> 3, cb = (c & 7) * 16;
      const char* src = (const char*)(Kb + (size_t)(kt * 64 + row) * 64);
      gload16(src + (cb ^ swz7(row)), Kl + c * 8);
    }
#pragma unroll
    for (int i = 0; i < 2; ++i) {  // V tile transposed into Vt[d][kv], swizzled writes
      int c = i * 256 + t;
      int row = c >> 3, d0 = (c & 7) * 8;
      short8 v8 = *(const short8*)(Vb + (size_t)(kt * 64 + row) * 64 + d0);
#pragma unroll
      for (int j = 0; j < 8; ++j) {
        int dd = d0 + j;
        *(unsigned short*)((char*)Vt + dd * 128 + ((row * 2) ^ swz7(dd))) = (unsigned short)v8[j];
      }
    }
    __syncthreads();
    // S = Q K^T  (16 q-rows per wave x 64 kv)
    f32x4 sacc[4] = {};
#pragma unroll
    for (int nt = 0; nt < 4; ++nt) {
#pragma unroll
      for (int ks = 0; ks < 2; ++ks) {
        int row = nt * 16 + lr;
        short8 bfr = *(const short8*)((const char*)Kl + row * 128 + ((ks * 64 + hi * 16) ^ swz7(row)));
        sacc[nt] = __builtin_amdgcn_mfma_f32_16x16x32_bf16(qf[ks], bfr, sacc[nt], 0, 0, 0);
      }
    }
    // online softmax (rows r=0..3 of this lane's hi-group; reduce across 16-lane group)
#pragma unroll
    for (int r = 0; r < 4; ++r) {
      float mx = fmaxf(fmaxf(sacc[0][r], sacc[1][r]), fmaxf(sacc[2][r], sacc[3][r]));
#pragma unroll
      for (int d = 1; d < 16; d <<= 1) mx = fmaxf(mx, __shfl_xor(mx, d, 64));
      float mnew = fmaxf(mrow[r], mx * 0.125f);
      float sc = __expf(mrow[r] - mnew);
#pragma unroll
      for (int dt = 0; dt < 4; ++dt) oacc[dt][r] *= sc;
      float rsum = 0.f;
      unsigned short pb[4];
#pragma unroll
      for (int nt = 0; nt < 4; ++nt) {
        float p = __expf(sacc[nt][r] * 0.125f - mnew);
        rsum += p;
        pb[nt] = f2b(p);
      }
#pragma unroll
      for (int d = 1; d < 16; d <<= 1) rsum += __shfl_xor(rsum, d, 64);
      lrow[r] = lrow[r] * sc + rsum;
      mrow[r] = mnew;
      int prow = hi * 4 + r;
#pragma unroll
      for (int nt = 0; nt < 4; ++nt)
        *(unsigned short*)((char*)Pl[w] + prow * 128 + (((nt * 16 + lr) * 2) ^ swz7(prow))) = pb[nt];
    }
    // O += P V   (A = P [16 x 64], B = V via Vt)
    short8 paf[2];
#pragma unroll
    for (int ks = 0; ks < 2; ++ks)
      paf[ks] = *(const short8*)((const char*)Pl[w] + lr * 128 + ((ks * 64 + hi * 16) ^ swz7(lr)));
#pragma unroll
    for (int dt = 0; dt < 4; ++dt) {
#pragma unroll
      for (int ks = 0; ks < 2; ++ks) {
        int vrow = dt * 16 + lr;
        short8 bfr = *(const short8*)((const char*)Vt + vrow * 128 + ((ks * 64 + hi * 16) ^ swz7(vrow)));
        oacc[dt] = __builtin_amdgcn_mfma_f32_16x16x32_bf16(paf[ks], bfr, oacc[dt], 0, 0, 0);
      }
    }
  }
  // epilogue: normalize, write attn output in [B*S][1024] bf16 (m-major for out-proj)
#pragma unroll
  for (int r = 0; r < 4; ++r) {
    float inv = 1.f / lrow[r];
    int s = qt * 64 + w * 16 + hi * 4 + r;
    size_t base = ((size_t)(bh >> 4) * 2048 + s) * 1024 + (size_t)(bh & 15) * 64;
#pragma unroll
    for (int dt = 0; dt < 4; ++dt) Oout[base + dt * 16 + lr] = f2b(oacc[dt][r] * inv);
  }
}

extern "C" void kernel_launch(void* const* d_in, const int* in_sizes, int n_in,
                              void* d_out, int out_size, void* d_ws, size_t ws_size,
                              hipStream_t stream) {
  const float* q   = (const float*)d_in[0];
  const float* k   = (const float*)d_in[1];
  const float* v   = (const float*)d_in[2];
  const float* w_q = (const float*)d_in[3];
  const float* b_q = (const float*)d_in[4];
  const float* w_k = (const float*)d_in[5];
  const float* b_k = (const float*)d_in[6];
  const float* w_v = (const float*)d_in[7];
  const float* b_v = (const float*)d_in[8];
  const float* w_o = (const float*)d_in[9];
  const float* b_o = (const float*)d_in[10];

  unsigned short* ws = (unsigned short*)d_ws;
  const size_t M1 = 1024 * 1024;
  unsigned short* qb = ws;            // [4096][1024] bf16
  unsigned short* kb = ws + 4 * M1;
  unsigned short* vb = ws + 8 * M1;
  unsigned short* wq = ws + 12 * M1;  // [1024][1024] bf16
  unsigned short* wk = ws + 13 * M1;
  unsigned short* wv = ws + 14 * M1;
  unsigned short* wo = ws + 15 * M1;
  unsigned short* Qh = ws + 16 * M1;  // [32][2048][64] bf16
  unsigned short* Kh = ws + 20 * M1;
  unsigned short* Vh = ws + 24 * M1;
  unsigned short* Ah = ws + 28 * M1;  // attn out [4096][1024] bf16

  cvt_bf16<<<2048, 256, 0, stream>>>(q, qb, 4194304);
  cvt_bf16<<<2048, 256, 0, stream>>>(k, kb, 4194304);
  cvt_bf16<<<2048, 256, 0, stream>>>(v, vb, 4194304);
  cvt_bf16<<<512, 256, 0, stream>>>(w_q, wq, 1048576);
  cvt_bf16<<<512, 256, 0, stream>>>(w_k, wk, 1048576);
  cvt_bf16<<<512, 256, 0, stream>>>(w_v, wv, 1048576);
  cvt_bf16<<<512, 256, 0, stream>>>(w_o, wo, 1048576);

  dim3 g(8, 32);
  gemm_bt<0><<<g, 256, 0, stream>>>(qb, wq, b_q, Qh);
  gemm_bt<0><<<g, 256, 0, stream>>>(kb, wk, b_k, Kh);
  gemm_bt<0><<<g, 256, 0, stream>>>(vb, wv, b_v, Vh);

  attn_fwd<<<1024, 256, 0, stream>>>(Qh, Kh, Vh, Ah);

  gemm_bt<1><<<g, 256, 0, stream>>>(Ah, wo, b_o, d_out);
}

// Round 8
// 304.654 us; speedup vs baseline: 1.1368x; 1.1368x over previous
//
#include <hip/hip_runtime.h>
#include <hip/hip_bf16.h>

// MHA forward: B=2, S=2048, D_MODEL=1024, H=16, D_K=64. fp32 in/out, bf16 MFMA compute.
// ws layout (ushort units, M = 1<<20):
//   qb 0-4M, kb 4-8M, vb 8-12M, wcat(wq|wk|wv) 12-15M, wo 16-17M,
//   Qh 17-21M, Kh 21-25M, Vtg 25-29M, ml 29-30M.
//   Op (fp32, 32MB) aliases 0-16M (qb/kb/vb/wcat dead after QKV gemm).
//   Ah (bf16) aliases Kh 21-25M (dead after attn).  Total 60MB <= proven 64MB.

typedef __attribute__((ext_vector_type(8))) short short8;
typedef __attribute__((ext_vector_type(4))) short short4_t;
typedef __attribute__((ext_vector_type(4))) float f32x4;

__device__ __forceinline__ unsigned short f2b(float f) {
  union { float f; unsigned u; } x; x.f = f;
  unsigned r = (x.u + 0x7FFFu + ((x.u >> 16) & 1u)) >> 16;
  return (unsigned short)r;
}

__device__ __forceinline__ int swz7(int row) { return ((row ^ (row >> 3)) & 7) << 4; }

__device__ __forceinline__ void gload16(const void* g, void* l) {
  __builtin_amdgcn_global_load_lds((const __attribute__((address_space(1))) void*)g,
                                   (__attribute__((address_space(3))) void*)l, 16, 0, 0);
}

// ---------------- fp32 -> bf16 convert ----------------
__global__ __launch_bounds__(256) void cvt_bf16(const float* __restrict__ s,
                                                unsigned short* __restrict__ d, int n) {
  int i = (blockIdx.x * 256 + threadIdx.x) * 8;
  if (i >= n) return;
  float4 a = *(const float4*)(s + i);
  float4 b = *(const float4*)(s + i + 4);
  short8 o;
  o[0] = (short)f2b(a.x); o[1] = (short)f2b(a.y); o[2] = (short)f2b(a.z); o[3] = (short)f2b(a.w);
  o[4] = (short)f2b(b.x); o[5] = (short)f2b(b.y); o[6] = (short)f2b(b.z); o[7] = (short)f2b(b.w);
  *(short8*)(d + i) = o;
}

// ---------------- GEMM: out[m,n] = sum_k A[m,k]*W[n,k] + bias[n] ----------------
// MODE 3: fused QKV (BN=128, grid.x=24): chunk=n0>>10 selects A/bias/output.
//         chunk 0 -> Qh head layout *0.125; chunk 1 -> Kh head layout; chunk 2 -> V^T [bh][d][s].
// MODE 1: fp32 out [4096][1024] (out-projection), BN=64.
template <int BN, int MODE>
__global__ __launch_bounds__(256, 2) void gemm_t(
    const unsigned short* __restrict__ A0, const unsigned short* __restrict__ A1,
    const unsigned short* __restrict__ A2, const unsigned short* __restrict__ Wt,
    const float* __restrict__ b0, const float* __restrict__ b1, const float* __restrict__ b2,
    void* __restrict__ O0, void* __restrict__ O1, void* __restrict__ O2) {
  constexpr int K = 1024;
  constexpr int NT = BN / 32;
  const int m0 = blockIdx.y * 128, n0 = blockIdx.x * BN;
  const int chunk = (MODE == 3) ? (n0 >> 10) : 0;
  const unsigned short* A = A0;
  const float* bias = b0;
  if (MODE == 3) {
    A = chunk == 0 ? A0 : chunk == 1 ? A1 : A2;
    bias = chunk == 0 ? b0 : chunk == 1 ? b1 : b2;
  }
  __shared__ __align__(16) unsigned short At[128 * 64];
  __shared__ __align__(16) unsigned short Bt[BN * 64];
  const int t = threadIdx.x;
  const int w = t >> 6, l = t & 63;
  const int wr = w >> 1, wc = w & 1;
  const int lr = l & 15, hi = l >> 4;
  f32x4 acc[4][NT] = {};
  for (int kt = 0; kt < 16; ++kt) {
    __syncthreads();
#pragma unroll
    for (int i = 0; i < 4; ++i) {  // A tile 128x64, pre-swizzled source -> linear LDS
      int c = i * 256 + t;
      int row = c >> 3, cb = (c & 7) * 16;
      const char* src = (const char*)(A + (size_t)(m0 + row) * K + kt * 64);
      gload16(src + (cb ^ swz7(row)), At + c * 8);
    }
#pragma unroll
    for (int i = 0; i < BN / 32; ++i) {  // B tile BNx64
      int c = i * 256 + t;
      int row = c >> 3, cb = (c & 7) * 16;
      const char* src = (const char*)(Wt + (size_t)(n0 + row) * K + kt * 64);
      gload16(src + (cb ^ swz7(row)), Bt + c * 8);
    }
    __syncthreads();
#pragma unroll
    for (int ks = 0; ks < 2; ++ks) {
      short8 af[4], bf[NT];
#pragma unroll
      for (int mt = 0; mt < 4; ++mt) {
        int row = wr * 64 + mt * 16 + lr;
        af[mt] = *(const short8*)((const char*)At + row * 128 + ((ks * 64 + hi * 16) ^ swz7(row)));
      }
#pragma unroll
      for (int nt = 0; nt < NT; ++nt) {
        int row = wc * (BN / 2) + nt * 16 + lr;
        bf[nt] = *(const short8*)((const char*)Bt + row * 128 + ((ks * 64 + hi * 16) ^ swz7(row)));
      }
#pragma unroll
      for (int mt = 0; mt < 4; ++mt)
#pragma unroll
        for (int nt = 0; nt < NT; ++nt)
          acc[mt][nt] = __builtin_amdgcn_mfma_f32_16x16x32_bf16(af[mt], bf[nt], acc[mt][nt], 0, 0, 0);
    }
  }
  if (MODE == 1) {
    float* O = (float*)O0;
#pragma unroll
    for (int nt = 0; nt < NT; ++nt) {
      int n = n0 + wc * (BN / 2) + nt * 16 + lr;
      float bn = bias[n];
#pragma unroll
      for (int mt = 0; mt < 4; ++mt)
#pragma unroll
        for (int r = 0; r < 4; ++r) {
          int m = m0 + wr * 64 + mt * 16 + hi * 4 + r;
          O[(size_t)m * 1024 + n] = acc[mt][nt][r] + bn;
        }
    }
  } else if (chunk <= 1) {  // Q or K -> head layout [bh][s][64]
    unsigned short* O = (unsigned short*)(chunk ? O1 : O0);
    const float sc = (chunk == 0) ? 0.125f : 1.0f;  // fold 1/sqrt(d_k) into Q
#pragma unroll
    for (int nt = 0; nt < NT; ++nt) {
      int n = (n0 + wc * (BN / 2) + nt * 16 + lr) & 1023;
      float bn = bias[n];
#pragma unroll
      for (int mt = 0; mt < 4; ++mt)
#pragma unroll
        for (int r = 0; r < 4; ++r) {
          int m = m0 + wr * 64 + mt * 16 + hi * 4 + r;
          float v = (acc[mt][nt][r] + bn) * sc;
          size_t dst = ((size_t)((m >> 11) * 16 + (n >> 6))) * (2048 * 64) +
                       (size_t)(m & 2047) * 64 + (n & 63);
          O[dst] = f2b(v);
        }
    }
  } else {  // V -> transposed per-head layout [bh][d=64][s=2048], packed 4x u16 stores
    unsigned short* O = (unsigned short*)O2;
#pragma unroll
    for (int nt = 0; nt < NT; ++nt) {
      int n = (n0 + wc * (BN / 2) + nt * 16 + lr) & 1023;
      float bn = bias[n];
#pragma unroll
      for (int mt = 0; mt < 4; ++mt) {
        int mb = m0 + wr * 64 + mt * 16 + hi * 4;
        short4_t pk;
#pragma unroll
        for (int r = 0; r < 4; ++r) pk[r] = (short)f2b(acc[mt][nt][r] + bn);
        size_t dst = ((size_t)((mb >> 11) * 16 + (n >> 6))) * (64 * 2048) +
                     (size_t)(n & 63) * 2048 + (mb & 2047);
        *(short4_t*)(O + dst) = pk;
      }
    }
  }
}

// ---------------- flash attention, KV-split x2 ----------------
// block = (half, bh, qt): 64 Q rows, KV range half*1024..+1024. Writes unnormalized
// fp32 partial O + (m,l) per row; merge kernel combines the two halves.
__global__ __launch_bounds__(256, 2) void attn_fwd(const unsigned short* __restrict__ Q,
                                                   const unsigned short* __restrict__ Kh,
                                                   const unsigned short* __restrict__ Vtg,
                                                   float* __restrict__ Op,
                                                   float* __restrict__ ml) {
  const int bid = blockIdx.x;
  const int qt = bid & 31, bh = (bid >> 5) & 31, hf = bid >> 10;
  const int t = threadIdx.x, w = t >> 6, l = t & 63;
  const int lr = l & 15, hi = l >> 4;
  __shared__ __align__(16) unsigned short Kl[64 * 64];
  __shared__ __align__(16) unsigned short Vl[64 * 64];  // V^T tile: [d=64][kv=64]
  __shared__ __align__(16) unsigned short Pl[4][16 * 64];
  const unsigned short* Qb = Q + (size_t)bh * 131072;
  const unsigned short* Kb = Kh + (size_t)bh * 131072 + (size_t)hf * 65536;
  const unsigned short* Vb = Vtg + (size_t)bh * 131072 + (size_t)hf * 1024;  // [d][s] rows stride 2048
  short8 qf[2];
#pragma unroll
  for (int ks = 0; ks < 2; ++ks)
    qf[ks] = *(const short8*)(Qb + (size_t)(qt * 64 + w * 16 + lr) * 64 + ks * 32 + hi * 8);
  f32x4 oacc[4] = {};
  float mrow[4], lrow[4];
#pragma unroll
  for (int r = 0; r < 4; ++r) { mrow[r] = -1e30f; lrow[r] = 0.f; }

  for (int kt = 0; kt < 16; ++kt) {
    __syncthreads();
#pragma unroll
    for (int i = 0; i < 2; ++i) {  // K tile [kv=64][d=64]
      int c = i * 256 + t;
      int row = c >> 3, cb = (c & 7) * 16;
      const char* src = (const char*)(Kb + (size_t)(kt * 64 + row) * 64);
      gload16(src + (cb ^ swz7(row)), Kl + c * 8);
    }
#pragma unroll
    for (int i = 0; i < 2; ++i) {  // V^T tile [d=64][kv=64] from [bh][d][s] global
      int c = i * 256 + t;
      int row = c >> 3, cb = (c & 7) * 16;
      const char* src = (const char*)(Vb + (size_t)row * 2048 + kt * 64);
      gload16(src + (cb ^ swz7(row)), Vl + c * 8);
    }
    __syncthreads();
    // S = Q K^T (Q pre-scaled by 1/8)
    f32x4 sacc[4] = {};
#pragma unroll
    for (int nt = 0; nt < 4; ++nt) {
#pragma unroll
      for (int ks = 0; ks < 2; ++ks) {
        int row = nt * 16 + lr;
        short8 bfr = *(const short8*)((const char*)Kl + row * 128 + ((ks * 64 + hi * 16) ^ swz7(row)));
        sacc[nt] = __builtin_amdgcn_mfma_f32_16x16x32_bf16(qf[ks], bfr, sacc[nt], 0, 0, 0);
      }
    }
    // online softmax: rows q = hi*4+r, reduce across the 16 lr lanes
#pragma unroll
    for (int r = 0; r < 4; ++r) {
      float mx = fmaxf(fmaxf(sacc[0][r], sacc[1][r]), fmaxf(sacc[2][r], sacc[3][r]));
#pragma unroll
      for (int d = 1; d < 16; d <<= 1) mx = fmaxf(mx, __shfl_xor(mx, d, 64));
      float mnew = fmaxf(mrow[r], mx);
      float sc = __expf(mrow[r] - mnew);
#pragma unroll
      for (int dt = 0; dt < 4; ++dt) oacc[dt][r] *= sc;
      float rsum = 0.f;
      unsigned short pb[4];
#pragma unroll
      for (int nt = 0; nt < 4; ++nt) {
        float p = __expf(sacc[nt][r] - mnew);
        rsum += p;
        pb[nt] = f2b(p);
      }
#pragma unroll
      for (int d = 1; d < 16; d <<= 1) rsum += __shfl_xor(rsum, d, 64);
      lrow[r] = lrow[r] * sc + rsum;
      mrow[r] = mnew;
      int prow = hi * 4 + r;
#pragma unroll
      for (int nt = 0; nt < 4; ++nt)
        *(unsigned short*)((char*)Pl[w] + prow * 128 + (((nt * 16 + lr) * 2) ^ swz7(prow))) = pb[nt];
    }
    // O += P V
    short8 paf[2];
#pragma unroll
    for (int ks = 0; ks < 2; ++ks)
      paf[ks] = *(const short8*)((const char*)Pl[w] + lr * 128 + ((ks * 64 + hi * 16) ^ swz7(lr)));
#pragma unroll
    for (int dt = 0; dt < 4; ++dt) {
#pragma unroll
      for (int ks = 0; ks < 2; ++ks) {
        int vrow = dt * 16 + lr;
        short8 bfr = *(const short8*)((const char*)Vl + vrow * 128 + ((ks * 64 + hi * 16) ^ swz7(vrow)));
        oacc[dt] = __builtin_amdgcn_mfma_f32_16x16x32_bf16(paf[ks], bfr, oacc[dt], 0, 0, 0);
      }
    }
  }
  // epilogue: unnormalized partial O (fp32) + per-row (m, l)
  const size_t ro = ((size_t)hf * 32 + bh) * 2048 + qt * 64 + w * 16;
#pragma unroll
  for (int r = 0; r < 4; ++r) {
    int sl = hi * 4 + r;
#pragma unroll
    for (int dt = 0; dt < 4; ++dt)
      Op[(ro + sl) * 64 + dt * 16 + lr] = oacc[dt][r];
    if (lr == 0) {
      ml[(ro + sl) * 2] = mrow[r];
      ml[(ro + sl) * 2 + 1] = lrow[r];
    }
  }
}

// ---------------- merge the two KV halves ----------------
__global__ __launch_bounds__(256) void merge_halves(const float* __restrict__ Op,
                                                    const float* __restrict__ ml,
                                                    unsigned short* __restrict__ Ah) {
  const int t = threadIdx.x;
  const int row = blockIdx.x * 32 + (t >> 3);  // 0..65535 = bh*2048+s
  const int d0 = (t & 7) * 8;
  const float ma = ml[(size_t)row * 2], la = ml[(size_t)row * 2 + 1];
  const float mb = ml[(size_t)(65536 + row) * 2], lb = ml[(size_t)(65536 + row) * 2 + 1];
  const float m = fmaxf(ma, mb);
  const float ea = __expf(ma - m), eb = __expf(mb - m);
  const float inv = 1.f / (la * ea + lb * eb);
  const float ca = ea * inv, cb = eb * inv;
  const float* o1 = Op + (size_t)row * 64 + d0;
  const float* o2 = o1 + (size_t)65536 * 64;
  float4 a0 = *(const float4*)o1, a1 = *(const float4*)(o1 + 4);
  float4 b0 = *(const float4*)o2, b1 = *(const float4*)(o2 + 4);
  short8 pk;
  pk[0] = (short)f2b(a0.x * ca + b0.x * cb); pk[1] = (short)f2b(a0.y * ca + b0.y * cb);
  pk[2] = (short)f2b(a0.z * ca + b0.z * cb); pk[3] = (short)f2b(a0.w * ca + b0.w * cb);
  pk[4] = (short)f2b(a1.x * ca + b1.x * cb); pk[5] = (short)f2b(a1.y * ca + b1.y * cb);
  pk[6] = (short)f2b(a1.z * ca + b1.z * cb); pk[7] = (short)f2b(a1.w * ca + b1.w * cb);
  const int bh = row >> 11, s = row & 2047;
  size_t dst = ((size_t)(bh >> 4) * 2048 + s) * 1024 + (size_t)(bh & 15) * 64 + d0;
  *(short8*)(Ah + dst) = pk;
}

extern "C" void kernel_launch(void* const* d_in, const int* in_sizes, int n_in,
                              void* d_out, int out_size, void* d_ws, size_t ws_size,
                              hipStream_t stream) {
  const float* q   = (const float*)d_in[0];
  const float* k   = (const float*)d_in[1];
  const float* v   = (const float*)d_in[2];
  const float* w_q = (const float*)d_in[3];
  const float* b_q = (const float*)d_in[4];
  const float* w_k = (const float*)d_in[5];
  const float* b_k = (const float*)d_in[6];
  const float* w_v = (const float*)d_in[7];
  const float* b_v = (const float*)d_in[8];
  const float* w_o = (const float*)d_in[9];
  const float* b_o = (const float*)d_in[10];

  unsigned short* ws = (unsigned short*)d_ws;
  const size_t M1 = 1u << 20;
  unsigned short* qb   = ws;             // [4096][1024] bf16
  unsigned short* kb   = ws + 4 * M1;
  unsigned short* vb   = ws + 8 * M1;
  unsigned short* wcat = ws + 12 * M1;   // wq|wk|wv  [3072][1024] bf16
  unsigned short* wo   = ws + 16 * M1;   // [1024][1024] bf16
  unsigned short* Qh   = ws + 17 * M1;   // [32][2048][64] bf16 (pre-scaled by 1/8)
  unsigned short* Kh   = ws + 21 * M1;   // [32][2048][64] bf16
  unsigned short* Vtg  = ws + 25 * M1;   // [32][64][2048] bf16 (V^T per head)
  float*          mlp  = (float*)(ws + 29 * M1);  // [2][32][2048][2] f32
  float*          Op   = (float*)ws;     // [2][32][2048][64] f32 (aliases dead qb..wcat)
  unsigned short* Ah   = ws + 21 * M1;   // attn out [4096][1024] bf16 (aliases dead Kh)

  cvt_bf16<<<2048, 256, 0, stream>>>(q, qb, 4194304);
  cvt_bf16<<<2048, 256, 0, stream>>>(k, kb, 4194304);
  cvt_bf16<<<2048, 256, 0, stream>>>(v, vb, 4194304);
  cvt_bf16<<<512, 256, 0, stream>>>(w_q, wcat, 1048576);
  cvt_bf16<<<512, 256, 0, stream>>>(w_k, wcat + M1, 1048576);
  cvt_bf16<<<512, 256, 0, stream>>>(w_v, wcat + 2 * M1, 1048576);
  cvt_bf16<<<512, 256, 0, stream>>>(w_o, wo, 1048576);

  gemm_t<128, 3><<<dim3(24, 32), 256, 0, stream>>>(qb, kb, vb, wcat, b_q, b_k, b_v,
                                                   Qh, Kh, Vtg);

  attn_fwd<<<2048, 256, 0, stream>>>(Qh, Kh, Vtg, Op, mlp);
  merge_halves<<<2048, 256, 0, stream>>>(Op, mlp, Ah);

  gemm_t<64, 1><<<dim3(16, 32), 256, 0, stream>>>(Ah, nullptr, nullptr, wo, b_o,
                                                  nullptr, nullptr, d_out, nullptr, nullptr);
}

// Round 11
// 301.299 us; speedup vs baseline: 1.1495x; 1.0111x over previous
//
#include <hip/hip_runtime.h>
#include <hip/hip_bf16.h>

// MHA forward: B=2, S=2048, D_MODEL=1024, H=16, D_K=64. fp32 in/out, bf16 MFMA compute.
// ws layout (ushort units, M = 1<<20):
//   qb 0-4M, kb 4-8M, vb 8-12M, wcat(wq|wk|wv) 12-15M, wo 16-17M,
//   Qh 17-21M, Kh 21-25M, Vtg 25-29M, ml 29-30M.
//   Op (fp32, 32MB) aliases 0-16M (qb/kb/vb/wcat dead after QKV gemm).
//   Ah (bf16) aliases Kh 21-25M (dead after attn).  Total 60MB <= proven 64MB.

typedef __attribute__((ext_vector_type(8))) short short8;
typedef __attribute__((ext_vector_type(4))) short short4_t;
typedef __attribute__((ext_vector_type(4))) float f32x4;

__device__ __forceinline__ unsigned short f2b(float f) {
  union { float f; unsigned u; } x; x.f = f;
  unsigned r = (x.u + 0x7FFFu + ((x.u >> 16) & 1u)) >> 16;
  return (unsigned short)r;
}

__device__ __forceinline__ int swz7(int row) { return ((row ^ (row >> 3)) & 7) << 4; }

__device__ __forceinline__ void gload16(const void* g, void* l) {
  __builtin_amdgcn_global_load_lds((const __attribute__((address_space(1))) void*)g,
                                   (__attribute__((address_space(3))) void*)l, 16, 0, 0);
}

// ---------------- fp32 -> bf16 convert ----------------
__global__ __launch_bounds__(256) void cvt_bf16(const float* __restrict__ s,
                                                unsigned short* __restrict__ d, int n) {
  int i = (blockIdx.x * 256 + threadIdx.x) * 8;
  if (i >= n) return;
  float4 a = *(const float4*)(s + i);
  float4 b = *(const float4*)(s + i + 4);
  short8 o;
  o[0] = (short)f2b(a.x); o[1] = (short)f2b(a.y); o[2] = (short)f2b(a.z); o[3] = (short)f2b(a.w);
  o[4] = (short)f2b(b.x); o[5] = (short)f2b(b.y); o[6] = (short)f2b(b.z); o[7] = (short)f2b(b.w);
  *(short8*)(d + i) = o;
}

// ---------------- GEMM: out[m,n] = sum_k A[m,k]*W[n,k] + bias[n] ----------------
// MODE 3: fused QKV (BN=128, grid.x=24): chunk=n0>>10 selects A/bias/output.
//         chunk 0 -> Qh head layout *0.125; chunk 1 -> Kh head layout; chunk 2 -> V^T [bh][d][s].
// MODE 1: fp32 out [4096][1024] (out-projection), BN=64.
template <int BN, int MODE>
__global__ __launch_bounds__(256, 2) void gemm_t(
    const unsigned short* __restrict__ A0, const unsigned short* __restrict__ A1,
    const unsigned short* __restrict__ A2, const unsigned short* __restrict__ Wt,
    const float* __restrict__ b0, const float* __restrict__ b1, const float* __restrict__ b2,
    void* __restrict__ O0, void* __restrict__ O1, void* __restrict__ O2) {
  constexpr int K = 1024;
  constexpr int NT = BN / 32;
  const int m0 = blockIdx.y * 128, n0 = blockIdx.x * BN;
  const int chunk = (MODE == 3) ? (n0 >> 10) : 0;
  const unsigned short* A = A0;
  const float* bias = b0;
  if (MODE == 3) {
    A = chunk == 0 ? A0 : chunk == 1 ? A1 : A2;
    bias = chunk == 0 ? b0 : chunk == 1 ? b1 : b2;
  }
  __shared__ __align__(16) unsigned short At[128 * 64];
  __shared__ __align__(16) unsigned short Bt[BN * 64];
  const int t = threadIdx.x;
  const int w = t >> 6, l = t & 63;
  const int wr = w >> 1, wc = w & 1;
  const int lr = l & 15, hi = l >> 4;
  f32x4 acc[4][NT] = {};
  for (int kt = 0; kt < 16; ++kt) {
    __syncthreads();
#pragma unroll
    for (int i = 0; i < 4; ++i) {  // A tile 128x64, pre-swizzled source -> linear LDS
      int c = i * 256 + t;
      int row = c >> 3, cb = (c & 7) * 16;
      const char* src = (const char*)(A + (size_t)(m0 + row) * K + kt * 64);
      gload16(src + (cb ^ swz7(row)), At + c * 8);
    }
#pragma unroll
    for (int i = 0; i < BN / 32; ++i) {  // B tile BNx64
      int c = i * 256 + t;
      int row = c >> 3, cb = (c & 7) * 16;
      const char* src = (const char*)(Wt + (size_t)(n0 + row) * K + kt * 64);
      gload16(src + (cb ^ swz7(row)), Bt + c * 8);
    }
    __syncthreads();
#pragma unroll
    for (int ks = 0; ks < 2; ++ks) {
      short8 af[4], bf[NT];
#pragma unroll
      for (int mt = 0; mt < 4; ++mt) {
        int row = wr * 64 + mt * 16 + lr;
        af[mt] = *(const short8*)((const char*)At + row * 128 + ((ks * 64 + hi * 16) ^ swz7(row)));
      }
#pragma unroll
      for (int nt = 0; nt < NT; ++nt) {
        int row = wc * (BN / 2) + nt * 16 + lr;
        bf[nt] = *(const short8*)((const char*)Bt + row * 128 + ((ks * 64 + hi * 16) ^ swz7(row)));
      }
#pragma unroll
      for (int mt = 0; mt < 4; ++mt)
#pragma unroll
        for (int nt = 0; nt < NT; ++nt)
          acc[mt][nt] = __builtin_amdgcn_mfma_f32_16x16x32_bf16(af[mt], bf[nt], acc[mt][nt], 0, 0, 0);
    }
  }
  if (MODE == 1) {
    float* O = (float*)O0;
#pragma unroll
    for (int nt = 0; nt < NT; ++nt) {
      int n = n0 + wc * (BN / 2) + nt * 16 + lr;
      float bn = bias[n];
#pragma unroll
      for (int mt = 0; mt < 4; ++mt)
#pragma unroll
        for (int r = 0; r < 4; ++r) {
          int m = m0 + wr * 64 + mt * 16 + hi * 4 + r;
          O[(size_t)m * 1024 + n] = acc[mt][nt][r] + bn;
        }
    }
  } else if (chunk <= 1) {  // Q or K -> head layout [bh][s][64]
    unsigned short* O = (unsigned short*)(chunk ? O1 : O0);
    const float sc = (chunk == 0) ? 0.125f : 1.0f;  // fold 1/sqrt(d_k) into Q
#pragma unroll
    for (int nt = 0; nt < NT; ++nt) {
      int n = (n0 + wc * (BN / 2) + nt * 16 + lr) & 1023;
      float bn = bias[n];
#pragma unroll
      for (int mt = 0; mt < 4; ++mt)
#pragma unroll
        for (int r = 0; r < 4; ++r) {
          int m = m0 + wr * 64 + mt * 16 + hi * 4 + r;
          float v = (acc[mt][nt][r] + bn) * sc;
          size_t dst = ((size_t)((m >> 11) * 16 + (n >> 6))) * (2048 * 64) +
                       (size_t)(m & 2047) * 64 + (n & 63);
          O[dst] = f2b(v);
        }
    }
  } else {  // V -> transposed per-head layout [bh][d=64][s=2048], packed 4x u16 stores
    unsigned short* O = (unsigned short*)O2;
#pragma unroll
    for (int nt = 0; nt < NT; ++nt) {
      int n = (n0 + wc * (BN / 2) + nt * 16 + lr) & 1023;
      float bn = bias[n];
#pragma unroll
      for (int mt = 0; mt < 4; ++mt) {
        int mb = m0 + wr * 64 + mt * 16 + hi * 4;
        short4_t pk;
#pragma unroll
        for (int r = 0; r < 4; ++r) pk[r] = (short)f2b(acc[mt][nt][r] + bn);
        size_t dst = ((size_t)((mb >> 11) * 16 + (n >> 6))) * (64 * 2048) +
                     (size_t)(n & 63) * 2048 + (mb & 2047);
        *(short4_t*)(O + dst) = pk;
      }
    }
  }
}

// ---------------- flash attention, KV-split x2, double-buffered K/V prefetch ----------------
// block = (half, bh, qt): 64 Q rows, KV range half*1024..+1024. Writes unnormalized
// fp32 partial O + (m,l) per row; merge kernel combines the two halves.
// T3-minimum pipeline: STAGE(t+1) issued BEFORE compute(t); single barrier per iter
// (compiler inserts vmcnt(0) before s_barrier, draining the prefetch that flew under compute).
__global__ __launch_bounds__(256, 2) void attn_fwd(const unsigned short* __restrict__ Q,
                                                   const unsigned short* __restrict__ Kh,
                                                   const unsigned short* __restrict__ Vtg,
                                                   float* __restrict__ Op,
                                                   float* __restrict__ ml) {
  const int bid = blockIdx.x;
  const int qt = bid & 31, bh = (bid >> 5) & 31, hf = bid >> 10;
  const int t = threadIdx.x, w = t >> 6, l = t & 63;
  const int lr = l & 15, hi = l >> 4;
  __shared__ __align__(16) unsigned short Kl[2][64 * 64];
  __shared__ __align__(16) unsigned short Vl[2][64 * 64];  // V^T tile: [d=64][kv=64]
  __shared__ __align__(16) unsigned short Pl[4][16 * 64];
  const unsigned short* Qb = Q + (size_t)bh * 131072;
  const unsigned short* Kb = Kh + (size_t)bh * 131072 + (size_t)hf * 65536;
  const unsigned short* Vb = Vtg + (size_t)bh * 131072 + (size_t)hf * 1024;  // [d][s] rows stride 2048
  short8 qf[2];
#pragma unroll
  for (int ks = 0; ks < 2; ++ks)
    qf[ks] = *(const short8*)(Qb + (size_t)(qt * 64 + w * 16 + lr) * 64 + ks * 32 + hi * 8);
  f32x4 oacc[4] = {};
  float mrow[4], lrow[4];
#pragma unroll
  for (int r = 0; r < 4; ++r) { mrow[r] = -1e30f; lrow[r] = 0.f; }

  // staging: K tile [kv=64][d=64] and V^T tile [d=64][kv=64], pre-swizzled sources
  auto STAGE = [&](int b, int kt) {
#pragma unroll
    for (int i = 0; i < 2; ++i) {
      int c = i * 256 + t;
      int row = c >> 3, cb = (c & 7) * 16;
      const char* srck = (const char*)(Kb + (size_t)(kt * 64 + row) * 64);
      gload16(srck + (cb ^ swz7(row)), Kl[b] + c * 8);
      const char* srcv = (const char*)(Vb + (size_t)row * 2048 + kt * 64);
      gload16(srcv + (cb ^ swz7(row)), Vl[b] + c * 8);
    }
  };

  STAGE(0, 0);
  __syncthreads();  // vmcnt(0) drain of prologue stage
  int buf = 0;
  for (int kt = 0; kt < 16; ++kt) {
    if (kt < 15) STAGE(buf ^ 1, kt + 1);  // prefetch next tile; flies under compute
    // S = Q K^T (Q pre-scaled by 1/8)
    f32x4 sacc[4] = {};
#pragma unroll
    for (int nt = 0; nt < 4; ++nt) {
#pragma unroll
      for (int ks = 0; ks < 2; ++ks) {
        int row = nt * 16 + lr;
        short8 bfr = *(const short8*)((const char*)Kl[buf] + row * 128 + ((ks * 64 + hi * 16) ^ swz7(row)));
        sacc[nt] = __builtin_amdgcn_mfma_f32_16x16x32_bf16(qf[ks], bfr, sacc[nt], 0, 0, 0);
      }
    }
    // online softmax: rows q = hi*4+r, reduce across the 16 lr lanes
#pragma unroll
    for (int r = 0; r < 4; ++r) {
      float mx = fmaxf(fmaxf(sacc[0][r], sacc[1][r]), fmaxf(sacc[2][r], sacc[3][r]));
#pragma unroll
      for (int d = 1; d < 16; d <<= 1) mx = fmaxf(mx, __shfl_xor(mx, d, 64));
      float mnew = fmaxf(mrow[r], mx);
      float sc = __expf(mrow[r] - mnew);
#pragma unroll
      for (int dt = 0; dt < 4; ++dt) oacc[dt][r] *= sc;
      float rsum = 0.f;
      unsigned short pb[4];
#pragma unroll
      for (int nt = 0; nt < 4; ++nt) {
        float p = __expf(sacc[nt][r] - mnew);
        rsum += p;
        pb[nt] = f2b(p);
      }
#pragma unroll
      for (int d = 1; d < 16; d <<= 1) rsum += __shfl_xor(rsum, d, 64);
      lrow[r] = lrow[r] * sc + rsum;
      mrow[r] = mnew;
      int prow = hi * 4 + r;
#pragma unroll
      for (int nt = 0; nt < 4; ++nt)
        *(unsigned short*)((char*)Pl[w] + prow * 128 + (((nt * 16 + lr) * 2) ^ swz7(prow))) = pb[nt];
    }
    // O += P V
    short8 paf[2];
#pragma unroll
    for (int ks = 0; ks < 2; ++ks)
      paf[ks] = *(const short8*)((const char*)Pl[w] + lr * 128 + ((ks * 64 + hi * 16) ^ swz7(lr)));
#pragma unroll
    for (int dt = 0; dt < 4; ++dt) {
#pragma unroll
      for (int ks = 0; ks < 2; ++ks) {
        int vrow = dt * 16 + lr;
        short8 bfr = *(const short8*)((const char*)Vl[buf] + vrow * 128 + ((ks * 64 + hi * 16) ^ swz7(vrow)));
        oacc[dt] = __builtin_amdgcn_mfma_f32_16x16x32_bf16(paf[ks], bfr, oacc[dt], 0, 0, 0);
      }
    }
    __syncthreads();  // drains prefetch (vmcnt(0)) + joins waves before buffer swap
    buf ^= 1;
  }
  // epilogue: unnormalized partial O (fp32) + per-row (m, l)
  const size_t ro = ((size_t)hf * 32 + bh) * 2048 + qt * 64 + w * 16;
#pragma unroll
  for (int r = 0; r < 4; ++r) {
    int sl = hi * 4 + r;
#pragma unroll
    for (int dt = 0; dt < 4; ++dt)
      Op[(ro + sl) * 64 + dt * 16 + lr] = oacc[dt][r];
    if (lr == 0) {
      ml[(ro + sl) * 2] = mrow[r];
      ml[(ro + sl) * 2 + 1] = lrow[r];
    }
  }
}

// ---------------- merge the two KV halves ----------------
__global__ __launch_bounds__(256) void merge_halves(const float* __restrict__ Op,
                                                    const float* __restrict__ ml,
                                                    unsigned short* __restrict__ Ah) {
  const int t = threadIdx.x;
  const int row = blockIdx.x * 32 + (t >> 3);  // 0..65535 = bh*2048+s
  const int d0 = (t & 7) * 8;
  const float ma = ml[(size_t)row * 2], la = ml[(size_t)row * 2 + 1];
  const float mb = ml[(size_t)(65536 + row) * 2], lb = ml[(size_t)(65536 + row) * 2 + 1];
  const float m = fmaxf(ma, mb);
  const float ea = __expf(ma - m), eb = __expf(mb - m);
  const float inv = 1.f / (la * ea + lb * eb);
  const float ca = ea * inv, cb = eb * inv;
  const float* o1 = Op + (size_t)row * 64 + d0;
  const float* o2 = o1 + (size_t)65536 * 64;
  float4 a0 = *(const float4*)o1, a1 = *(const float4*)(o1 + 4);
  float4 b0 = *(const float4*)o2, b1 = *(const float4*)(o2 + 4);
  short8 pk;
  pk[0] = (short)f2b(a0.x * ca + b0.x * cb); pk[1] = (short)f2b(a0.y * ca + b0.y * cb);
  pk[2] = (short)f2b(a0.z * ca + b0.z * cb); pk[3] = (short)f2b(a0.w * ca + b0.w * cb);
  pk[4] = (short)f2b(a1.x * ca + b1.x * cb); pk[5] = (short)f2b(a1.y * ca + b1.y * cb);
  pk[6] = (short)f2b(a1.z * ca + b1.z * cb); pk[7] = (short)f2b(a1.w * ca + b1.w * cb);
  const int bh = row >> 11, s = row & 2047;
  size_t dst = ((size_t)(bh >> 4) * 2048 + s) * 1024 + (size_t)(bh & 15) * 64 + d0;
  *(short8*)(Ah + dst) = pk;
}

extern "C" void kernel_launch(void* const* d_in, const int* in_sizes, int n_in,
                              void* d_out, int out_size, void* d_ws, size_t ws_size,
                              hipStream_t stream) {
  const float* q   = (const float*)d_in[0];
  const float* k   = (const float*)d_in[1];
  const float* v   = (const float*)d_in[2];
  const float* w_q = (const float*)d_in[3];
  const float* b_q = (const float*)d_in[4];
  const float* w_k = (const float*)d_in[5];
  const float* b_k = (const float*)d_in[6];
  const float* w_v = (const float*)d_in[7];
  const float* b_v = (const float*)d_in[8];
  const float* w_o = (const float*)d_in[9];
  const float* b_o = (const float*)d_in[10];

  unsigned short* ws = (unsigned short*)d_ws;
  const size_t M1 = 1u << 20;
  unsigned short* qb   = ws;             // [4096][1024] bf16
  unsigned short* kb   = ws + 4 * M1;
  unsigned short* vb   = ws + 8 * M1;
  unsigned short* wcat = ws + 12 * M1;   // wq|wk|wv  [3072][1024] bf16
  unsigned short* wo   = ws + 16 * M1;   // [1024][1024] bf16
  unsigned short* Qh   = ws + 17 * M1;   // [32][2048][64] bf16 (pre-scaled by 1/8)
  unsigned short* Kh   = ws + 21 * M1;   // [32][2048][64] bf16
  unsigned short* Vtg  = ws + 25 * M1;   // [32][64][2048] bf16 (V^T per head)
  float*          mlp  = (float*)(ws + 29 * M1);  // [2][32][2048][2] f32
  float*          Op   = (float*)ws;     // [2][32][2048][64] f32 (aliases dead qb..wcat)
  unsigned short* Ah   = ws + 21 * M1;   // attn out [4096][1024] bf16 (aliases dead Kh)

  cvt_bf16<<<2048, 256, 0, stream>>>(q, qb, 4194304);
  cvt_bf16<<<2048, 256, 0, stream>>>(k, kb, 4194304);
  cvt_bf16<<<2048, 256, 0, stream>>>(v, vb, 4194304);
  cvt_bf16<<<512, 256, 0, stream>>>(w_q, wcat, 1048576);
  cvt_bf16<<<512, 256, 0, stream>>>(w_k, wcat + M1, 1048576);
  cvt_bf16<<<512, 256, 0, stream>>>(w_v, wcat + 2 * M1, 1048576);
  cvt_bf16<<<512, 256, 0, stream>>>(w_o, wo, 1048576);

  gemm_t<128, 3><<<dim3(24, 32), 256, 0, stream>>>(qb, kb, vb, wcat, b_q, b_k, b_v,
                                                   Qh, Kh, Vtg);

  attn_fwd<<<2048, 256, 0, stream>>>(Qh, Kh, Vtg, Op, mlp);
  merge_halves<<<2048, 256, 0, stream>>>(Op, mlp, Ah);

  gemm_t<64, 1><<<dim3(16, 32), 256, 0, stream>>>(Ah, nullptr, nullptr, wo, b_o,
                                                  nullptr, nullptr, d_out, nullptr, nullptr);
}